// Round 1
// 17038.019 us; speedup vs baseline: 1.3923x; 1.3923x over previous
//
#include <hip/hip_runtime.h>
#include <cstdint>
#include <cstddef>

// ---------------------------------------------------------------------------
// MyLSTM on MI355X.
// Phase 1: xg[B*T,4H] = x @ W + bias  (bf16 MFMA 16x16x32, 128x128 tiles)
// Phase 2: per-batch recurrence, 128 blocks x 1024 threads (split-k over the
//          512-long h-dot: half 0 owns k in [0,256), half 1 owns [256,512)),
//          R bf16 streamed from L2 with explicit depth-2 prefetch, h
//          double-buffered in LDS, c in registers, fp32 math.
// Gate layout along 4H: [i, f, g, o].
// ---------------------------------------------------------------------------

typedef __attribute__((ext_vector_type(8))) __bf16 bf16x8;
typedef __attribute__((ext_vector_type(4))) float floatx4;

__device__ __forceinline__ unsigned short f2bf(float f) {
  union { float f; uint32_t u; } v; v.f = f;
  uint32_t u = v.u;
  uint32_t r = (u + 0x7fffu + ((u >> 16) & 1u)) >> 16;  // RNE
  return (unsigned short)r;
}
__device__ __forceinline__ float bflo(uint32_t u) {
  union { uint32_t u; float f; } v; v.u = u << 16; return v.f;
}
__device__ __forceinline__ float bfhi(uint32_t u) {
  union { uint32_t u; float f; } v; v.u = u & 0xffff0000u; return v.f;
}
__device__ __forceinline__ float bf2f(unsigned short s) {
  union { uint32_t u; float f; } v; v.u = ((uint32_t)s) << 16; return v.f;
}

// ---------------------------- converters -----------------------------------

// x fp32 -> bf16 (ushort), packed pairs, order preserved.
__global__ void cvt_x_kernel(const float4* __restrict__ x, uint2* __restrict__ xbf, int n4) {
  int stride = gridDim.x * blockDim.x;
  for (int i = blockIdx.x * blockDim.x + threadIdx.x; i < n4; i += stride) {
    float4 v = x[i];
    uint2 o;
    o.x = (uint32_t)f2bf(v.x) | ((uint32_t)f2bf(v.y) << 16);
    o.y = (uint32_t)f2bf(v.z) | ((uint32_t)f2bf(v.w) << 16);
    xbf[i] = o;
  }
}

// W fp32 [512][2048] -> Wt bf16 [2048][512] (transposed so GEMM B-frags read
// contiguous-k rows, same LDS pattern as A — the m90..m97 "BT" structure).
__global__ void cvt_wt_kernel(const float* __restrict__ W, unsigned short* __restrict__ wt) {
  int id = blockIdx.x * 256 + threadIdx.x;   // 1048576 total
  int k = id >> 11, n = id & 2047;
  wt[n * 512 + k] = f2bf(W[id]);
}

// R fp32 [512][2048] -> Rq: for k8 in [0,64), n in [0,2048): uint4 where dword q
// packs (R[8k8+2q][n] low, R[8k8+2q+1][n] high). One 16B coalesced load gives a
// thread 8 consecutive-k weights for its column n.
__global__ void cvt_rq_kernel(const float* __restrict__ R, uint4* __restrict__ rq) {
  int id = blockIdx.x * 256 + threadIdx.x;   // 131072 = 64*2048
  int k8 = id >> 11, n = id & 2047;
  const float* base = R + (size_t)(k8 * 8) * 2048 + n;
  uint32_t d[4];
#pragma unroll
  for (int q = 0; q < 4; ++q) {
    uint32_t lo = f2bf(base[(2 * q) * 2048]);
    uint32_t hi = f2bf(base[(2 * q + 1) * 2048]);
    d[q] = lo | (hi << 16);
  }
  rq[id] = make_uint4(d[0], d[1], d[2], d[3]);
}

// ------------------------------ front GEMM ----------------------------------

__device__ __forceinline__ void xg_store(float* C, size_t idx, float v) { C[idx] = v; }
__device__ __forceinline__ void xg_store(unsigned short* C, size_t idx, float v) { C[idx] = f2bf(v); }

// A: x bf16 [131072][512] row-major; Bt: Wt bf16 [2048][512]; C: xg [131072][2048].
// Tile 128x128x(BK=64), 256 threads = 4 waves in 2x2, each wave 4x4 16x16 frags.
template <typename XG>
__global__ __launch_bounds__(256, 2) void gemm_kernel(
    const unsigned short* __restrict__ A, const unsigned short* __restrict__ Bt,
    const float* __restrict__ bias, XG* __restrict__ C) {
  // +8 pad per row: 144B row stride -> frag reads are 2-way bank aliased (free).
  __shared__ __align__(16) unsigned short ldsA[128 * 72];
  __shared__ __align__(16) unsigned short ldsB[128 * 72];

  const int n0 = blockIdx.x * 128;
  const int m0 = blockIdx.y * 128;
  const int tid = threadIdx.x;
  const int lane = tid & 63;
  const int wave = tid >> 6;
  const int wm = wave >> 1, wn = wave & 1;
  const int l15 = lane & 15, quad = lane >> 4;
  const int seg = tid & 7, row0 = tid >> 3;

  floatx4 acc[4][4];
#pragma unroll
  for (int mi = 0; mi < 4; ++mi)
#pragma unroll
    for (int ni = 0; ni < 4; ++ni) acc[mi][ni] = (floatx4)0.0f;

  for (int k0 = 0; k0 < 512; k0 += 64) {
    __syncthreads();
#pragma unroll
    for (int it = 0; it < 4; ++it) {
      int row = row0 + it * 32;
      *(uint4*)&ldsA[row * 72 + seg * 8] =
          *(const uint4*)&A[(size_t)(m0 + row) * 512 + k0 + seg * 8];
      *(uint4*)&ldsB[row * 72 + seg * 8] =
          *(const uint4*)&Bt[(size_t)(n0 + row) * 512 + k0 + seg * 8];
    }
    __syncthreads();
#pragma unroll
    for (int kk = 0; kk < 2; ++kk) {
      bf16x8 af[4], bfv[4];
#pragma unroll
      for (int mi = 0; mi < 4; ++mi)
        af[mi] = *(const bf16x8*)&ldsA[(wm * 64 + mi * 16 + l15) * 72 + kk * 32 + quad * 8];
#pragma unroll
      for (int ni = 0; ni < 4; ++ni)
        bfv[ni] = *(const bf16x8*)&ldsB[(wn * 64 + ni * 16 + l15) * 72 + kk * 32 + quad * 8];
#pragma unroll
      for (int mi = 0; mi < 4; ++mi)
#pragma unroll
        for (int ni = 0; ni < 4; ++ni)
          acc[mi][ni] = __builtin_amdgcn_mfma_f32_16x16x32_bf16(af[mi], bfv[ni], acc[mi][ni], 0, 0, 0);
    }
  }

  // C/D layout (m89-verified): col = lane&15, row = quad*4 + reg.
#pragma unroll
  for (int mi = 0; mi < 4; ++mi)
#pragma unroll
    for (int ni = 0; ni < 4; ++ni) {
      int gr = m0 + wm * 64 + mi * 16 + quad * 4;
      int gc = n0 + wn * 64 + ni * 16 + l15;
      float bv = bias[gc];
#pragma unroll
      for (int r = 0; r < 4; ++r)
        xg_store(C, (size_t)(gr + r) * 2048 + gc, acc[mi][ni][r] + bv);
    }
}

// ------------------------------ recurrence ----------------------------------

__device__ __forceinline__ float xgld(const float* p) { return *p; }
__device__ __forceinline__ float xgld(const unsigned short* p) { return bf2f(*p); }

__device__ __forceinline__ float dot8(float acc, uint4 r, float4 h0, float4 h1) {
  acc = fmaf(bflo(r.x), h0.x, acc);
  acc = fmaf(bfhi(r.x), h0.y, acc);
  acc = fmaf(bflo(r.y), h0.z, acc);
  acc = fmaf(bfhi(r.y), h0.w, acc);
  acc = fmaf(bflo(r.z), h1.x, acc);
  acc = fmaf(bfhi(r.z), h1.y, acc);
  acc = fmaf(bflo(r.w), h1.z, acc);
  acc = fmaf(bfhi(r.w), h1.w, acc);
  return acc;
}

__device__ __forceinline__ void ld4(const uint4* __restrict__ q,
                                    uint4& i, uint4& f, uint4& g, uint4& o) {
  i = q[0]; f = q[512]; g = q[1024]; o = q[1536];
}

__device__ __forceinline__ float sigf(float x) { return 1.0f / (1.0f + __expf(-x)); }
__device__ __forceinline__ float tanh_fast(float x) {
  float xx = fminf(fmaxf(x, -9.0f), 9.0f);
  float t = __expf(2.0f * xx);
  return (t - 1.0f) / (t + 1.0f);
}

// One block per batch element, 1024 threads = 16 waves (4/SIMD for latency
// hiding). Thread (half, j): j = tid&511 owns hidden unit j, half = tid>>9
// owns k-range [half*256, half*256+256) of all 4 gate dots (split-k).
// Half 1 deposits partial sums in LDS; half 0 combines, applies gates, keeps
// c in a register, writes h. R loads are explicitly depth-2 prefetched so
// 8 dwordx4 per thread stay in flight across the FMA bursts.
template <typename XG>
__global__ __launch_bounds__(1024, 4) void lstm_rec_kernel(
    const uint4* __restrict__ Rq, const XG* __restrict__ xg, float* __restrict__ out) {
  __shared__ __align__(16) float hbuf[2][512];
  __shared__ __align__(16) float psum[4][512];
  const int b = blockIdx.x;
  const int tid = threadIdx.x;
  const int j = tid & 511;
  const int half = tid >> 9;

  float c = 0.0f;
  if (tid < 512) { hbuf[0][tid] = 0.0f; hbuf[1][tid] = 0.0f; }
  __syncthreads();

  const XG* xr = xg + (size_t)b * (1024 * 2048);
  float* outr = out + (size_t)b * (1024 * 512);
  // This thread's R panel: k8 in [half*32, half*32+32), column j (4 gates).
  const uint4* rp = Rq + ((size_t)(half * 32) << 11) + j;

  // xg preload for t=0 (half 0 accumulates the xg term).
  float a0n = 0.0f, a1n = 0.0f, a2n = 0.0f, a3n = 0.0f;
  if (half == 0) {
    a0n = xgld(xr + j);        a1n = xgld(xr + 512 + j);
    a2n = xgld(xr + 1024 + j); a3n = xgld(xr + 1536 + j);
  }

  for (int t = 0; t < 1024; ++t) {
    float a0 = a0n, a1 = a1n, a2 = a2n, a3 = a3n;
    // Prefetch next step's xg; it lands while this step's dots run.
    const XG* xp = xr + (t < 1023 ? 2048 : 0);
    if (half == 0) {
      a0n = xgld(xp + j);        a1n = xgld(xp + 512 + j);
      a2n = xgld(xp + 1024 + j); a3n = xgld(xp + 1536 + j);
    }
    const float4* hv = (const float4*)(hbuf[t & 1] + (half << 8));

    // Depth-2 software pipeline over the 32 k8-chunks of this half.
    uint4 Ai, Af, Ag, Ao, Bi, Bf, Bg, Bo, Ni, Nf, Ng, No;
    ld4(rp, Ai, Af, Ag, Ao);
    ld4(rp + ((size_t)1 << 11), Bi, Bf, Bg, Bo);
#pragma unroll 4
    for (int kk = 0; kk < 32; ++kk) {
      int kn = (kk + 2 < 32) ? kk + 2 : 31;   // clamped redundant tail loads (L1-hit)
      ld4(rp + ((size_t)kn << 11), Ni, Nf, Ng, No);
      float4 h0 = hv[2 * kk];
      float4 h1 = hv[2 * kk + 1];
      a0 = dot8(a0, Ai, h0, h1);
      a1 = dot8(a1, Af, h0, h1);
      a2 = dot8(a2, Ag, h0, h1);
      a3 = dot8(a3, Ao, h0, h1);
      Ai = Bi; Af = Bf; Ag = Bg; Ao = Bo;
      Bi = Ni; Bf = Nf; Bg = Ng; Bo = No;
    }

    if (half == 1) {
      psum[0][j] = a0; psum[1][j] = a1; psum[2][j] = a2; psum[3][j] = a3;
    }
    __syncthreads();   // psum visible; hbuf[t&1] reads all done
    if (half == 0) {
      a0 += psum[0][j]; a1 += psum[1][j]; a2 += psum[2][j]; a3 += psum[3][j];
      float ig = sigf(a0);
      float fg = sigf(a1);
      float gg = tanh_fast(a2);
      float og = sigf(a3);
      c = tanh_fast(fg * c + ig * gg);   // faithful quirk: tanh'd cell carried
      float hn = og * c;
      outr[j] = hn;
      hbuf[(t + 1) & 1][j] = hn;
    }
    __syncthreads();   // h(t+1) visible before next step's reads
    xr += 2048;
    outr += 512;
  }
}

// ------------------------------ launcher ------------------------------------

extern "C" void kernel_launch(void* const* d_in, const int* in_sizes, int n_in,
                              void* d_out, int out_size, void* d_ws, size_t ws_size,
                              hipStream_t stream) {
  const float* x = (const float*)d_in[0];     // [128,1024,512]
  const float* W = (const float*)d_in[1];     // [512,2048]
  const float* R = (const float*)d_in[2];     // [512,2048]
  const float* bias = (const float*)d_in[3];  // [2048]
  float* out = (float*)d_out;                 // [128,1024,512]

  char* ws = (char*)d_ws;
  const size_t off_xbf = 0;                   // 134,217,728 B  (x bf16)
  const size_t off_wt = 134217728;            //   2,097,152 B  (W^T bf16)
  const size_t off_rq = 136314880;            //   2,097,152 B  (R packed bf16)
  const size_t off_xg = 138412032;            //  xg: 1 GiB fp32 or 512 MiB bf16
  unsigned short* xbf = (unsigned short*)(ws + off_xbf);
  unsigned short* wt = (unsigned short*)(ws + off_wt);
  uint4* rq = (uint4*)(ws + off_rq);
  void* xgp = (void*)(ws + off_xg);

  const bool xg_f32 = ws_size >= off_xg + 1073741824ull;
  const bool xg_bf16_fits = ws_size >= off_xg + 536870912ull;

  hipLaunchKernelGGL(cvt_x_kernel, dim3(2048), dim3(256), 0, stream,
                     (const float4*)x, (uint2*)xbf, 16777216);
  hipLaunchKernelGGL(cvt_wt_kernel, dim3(4096), dim3(256), 0, stream, W, wt);
  hipLaunchKernelGGL(cvt_rq_kernel, dim3(512), dim3(256), 0, stream, R, rq);

  if (xg_f32) {
    hipLaunchKernelGGL((gemm_kernel<float>), dim3(16, 1024), dim3(256), 0, stream,
                       xbf, wt, bias, (float*)xgp);
    hipLaunchKernelGGL((lstm_rec_kernel<float>), dim3(128), dim3(1024), 0, stream,
                       rq, (const float*)xgp, out);
  } else if (xg_bf16_fits) {
    hipLaunchKernelGGL((gemm_kernel<unsigned short>), dim3(16, 1024), dim3(256), 0, stream,
                       xbf, wt, bias, (unsigned short*)xgp);
    hipLaunchKernelGGL((lstm_rec_kernel<unsigned short>), dim3(128), dim3(1024), 0, stream,
                       rq, (const unsigned short*)xgp, out);
  }
  // If neither fits, output stays poisoned -> visible failure (ws too small).
}